// Round 2
// baseline (659.565 us; speedup 1.0000x reference)
//
#include <hip/hip_runtime.h>

// Problem constants (fixed by the reference): B=256, N=2048, D=128, ANCHOR=0
#define B_SZ    256
#define N_NODES 2048
#define D_DIM   128

typedef __attribute__((ext_vector_type(8))) short short8;   // 8 bf16 (MFMA A/B frag)
typedef __attribute__((ext_vector_type(4))) float f32x4;    // MFMA C/D frag

// ---- workspace layout (bytes) ----
#define WS_W1BF    0          // 128*256 bf16 = 65536
#define WS_CNT     65536      // 256 * 4
#define WS_SCRATCH 66560      // 256 blocks * 32768 floats * 4 = 33554432

// RNE fp32->bf16 pack of two floats into one uint (lo = first)
__device__ __forceinline__ unsigned pk2(float x, float y) {
    unsigned a = __float_as_uint(x), b = __float_as_uint(y);
    a += 0x7fffu + ((a >> 16) & 1u);
    b += 0x7fffu + ((b >> 16) & 1u);
    return (a >> 16) | (b & 0xffff0000u);
}

__device__ __forceinline__ short8 pack8(float4 a, float4 b) {
    union { unsigned u[4]; short8 s; } r;
    r.u[0] = pk2(a.x, a.y); r.u[1] = pk2(a.z, a.w);
    r.u[2] = pk2(b.x, b.y); r.u[3] = pk2(b.z, b.w);
    return r.s;
}

__device__ __forceinline__ float bf2f(short s) {
    return __uint_as_float(((unsigned)(unsigned short)s) << 16);
}

// ---- W1 (128x256 fp32, row-major [d][k]) -> bf16 same layout ----
__global__ void k_prep_w1(const float* __restrict__ W1, unsigned* __restrict__ w1bf) {
    int i = blockIdx.x * 256 + threadIdx.x;           // 16384 float2 pairs
    float2 f = ((const float2*)W1)[i];
    w1bf[i] = pk2(f.x, f.y);
}

// ---- histogram of batch_idx over non-anchor rows (for the b2*count term) ----
__global__ void k_hist(const int* __restrict__ bidx, int* __restrict__ count) {
    __shared__ int lh[256];
    int t = threadIdx.x;
    lh[t] = 0;
    __syncthreads();
    int base = blockIdx.x * 1024 + t * 4;
    int4 v = ((const int4*)bidx)[blockIdx.x * 256 + t];
    if (((base + 0) & 2047) != 0) atomicAdd(&lh[v.x], 1);
    if (((base + 1) & 2047) != 0) atomicAdd(&lh[v.y], 1);
    if (((base + 2) & 2047) != 0) atomicAdd(&lh[v.z], 1);
    if (((base + 3) & 2047) != 0) atomicAdd(&lh[v.w], 1);
    __syncthreads();
    if (lh[t]) atomicAdd(&count[t], lh[t]);
}

// ---- main: stream batch b's 2048 rows; K=128 MFMA (emb half only; target half
//      folded into per-block bias tb); segment-accumulate in 132KB LDS ----
#define SACC_STRIDE 129   // 256 segs * 129 floats: ds_add bank spread (seg*129+col)%32

__global__ __launch_bounds__(1024) void k_main(
    const float* __restrict__ embs, const float* __restrict__ W1,
    const float* __restrict__ b1, const short* __restrict__ w1bf,
    const int* __restrict__ bidx, float* __restrict__ scratch)
{
    __shared__ float sacc[B_SZ * SACC_STRIDE];  // 132096 B
    __shared__ float tbuf[D_DIM];               // tb[d] = b1[d] + tgt . W1_tgt[d]
    __shared__ float t2buf[D_DIM];              // tgt_bf . W1emb_bf[d] (anchor row gemm)
    __shared__ float tgtf[D_DIM];               // target row fp32
    __shared__ float tgtb[D_DIM];               // target row bf16-rounded (as fp32)

    int tid = threadIdx.x;
    int b   = blockIdx.x;

    for (int i = tid; i < B_SZ * SACC_STRIDE; i += 1024) sacc[i] = 0.f;

    if (tid < D_DIM) {
        float v = embs[(b << 11) * D_DIM + tid];   // anchor row 0 of batch b
        tgtf[tid] = v;
        unsigned ub = __float_as_uint(v);
        ub += 0x7fffu + ((ub >> 16) & 1u);
        tgtb[tid] = __uint_as_float(ub & 0xffff0000u);
    }
    __syncthreads();

    if (tid < 128) {
        // tb[d]: fp32 target-half dot + bias (accurate; shared by all rows)
        float s = b1[tid];
        const float4* w = (const float4*)(W1 + tid * 256);
#pragma unroll
        for (int k = 0; k < 32; k++) {
            float4 wv = w[k];
            s += tgtf[4 * k + 0] * wv.x + tgtf[4 * k + 1] * wv.y
               + tgtf[4 * k + 2] * wv.z + tgtf[4 * k + 3] * wv.w;
        }
        tbuf[tid] = s;
    } else if (tid < 256) {
        // t2[d]: anchor row's emb-half gemm in the SAME bf16 arithmetic as MFMA
        int d = tid - 128;
        float s = 0.f;
        const short8* wr = (const short8*)(w1bf + d * 256 + 128);
#pragma unroll
        for (int k8 = 0; k8 < 16; k8++) {
            short8 v = wr[k8];
#pragma unroll
            for (int j = 0; j < 8; j++) s += tgtb[k8 * 8 + j] * bf2f(v[j]);
        }
        t2buf[d] = s;
    }
    __syncthreads();

    // anchor row's h, held in registers of threads 0..127 for end-of-kernel subtract
    float h_anchor = 0.f;
    int   seg0 = 0;
    if (tid < 128) {
        h_anchor = fmaxf(t2buf[tid] + tbuf[tid], 0.f);
        seg0 = bidx[b << 11];
    }

    int lane = tid & 63, wid = tid >> 6;
    int rt = wid & 3;            // row-tile (16 rows)
    int cg = wid >> 2;           // col-group (32 cols)
    int q = lane >> 4, i15 = lane & 15;
    int colc = cg * 32 + i15;
    float tb0 = tbuf[colc], tb1 = tbuf[colc + 16];

    // B fragments: W1emb[n][k], n = cg*32 + ct*16 + i15, k = kt*32 + q*8 .. +8
    short8 bf[4][2];
#pragma unroll
    for (int kt = 0; kt < 4; kt++)
#pragma unroll
        for (int ct = 0; ct < 2; ct++)
            bf[kt][ct] = *(const short8*)(w1bf + (cg * 32 + ct * 16 + i15) * 256
                                          + 128 + kt * 32 + q * 8);

    const float* abase = embs + ((b << 11) + rt * 16 + i15) * D_DIM + q * 8;
    int crow = rt * 16 + q * 4;          // local C row base within iter tile
    int rbid = (b << 11) + crow;

    // ---- barrier-free main loop: 32 iters x 64 rows ----
    for (int it = 0; it < 32; it++) {
        const float* ap = abase + it * 64 * D_DIM;
        short8 a0 = pack8(*(const float4*)(ap + 0),  *(const float4*)(ap + 4));
        short8 a1 = pack8(*(const float4*)(ap + 32), *(const float4*)(ap + 36));
        short8 a2 = pack8(*(const float4*)(ap + 64), *(const float4*)(ap + 68));
        short8 a3 = pack8(*(const float4*)(ap + 96), *(const float4*)(ap + 100));

        int r = rbid + it * 64;
        int s0 = bidx[r], s1 = bidx[r + 1], s2 = bidx[r + 2], s3 = bidx[r + 3];

        f32x4 m0 = {0.f, 0.f, 0.f, 0.f}, m1 = {0.f, 0.f, 0.f, 0.f};
        m0 = __builtin_amdgcn_mfma_f32_16x16x32_bf16(a0, bf[0][0], m0, 0, 0, 0);
        m1 = __builtin_amdgcn_mfma_f32_16x16x32_bf16(a0, bf[0][1], m1, 0, 0, 0);
        m0 = __builtin_amdgcn_mfma_f32_16x16x32_bf16(a1, bf[1][0], m0, 0, 0, 0);
        m1 = __builtin_amdgcn_mfma_f32_16x16x32_bf16(a1, bf[1][1], m1, 0, 0, 0);
        m0 = __builtin_amdgcn_mfma_f32_16x16x32_bf16(a2, bf[2][0], m0, 0, 0, 0);
        m1 = __builtin_amdgcn_mfma_f32_16x16x32_bf16(a2, bf[2][1], m1, 0, 0, 0);
        m0 = __builtin_amdgcn_mfma_f32_16x16x32_bf16(a3, bf[3][0], m0, 0, 0, 0);
        m1 = __builtin_amdgcn_mfma_f32_16x16x32_bf16(a3, bf[3][1], m1, 0, 0, 0);

        // h = relu(gemm + tb); segment-accumulate (ds_add_f32, no barrier needed)
        atomicAdd(&sacc[s0 * SACC_STRIDE + colc],      fmaxf(m0[0] + tb0, 0.f));
        atomicAdd(&sacc[s0 * SACC_STRIDE + colc + 16], fmaxf(m1[0] + tb1, 0.f));
        atomicAdd(&sacc[s1 * SACC_STRIDE + colc],      fmaxf(m0[1] + tb0, 0.f));
        atomicAdd(&sacc[s1 * SACC_STRIDE + colc + 16], fmaxf(m1[1] + tb1, 0.f));
        atomicAdd(&sacc[s2 * SACC_STRIDE + colc],      fmaxf(m0[2] + tb0, 0.f));
        atomicAdd(&sacc[s2 * SACC_STRIDE + colc + 16], fmaxf(m1[2] + tb1, 0.f));
        atomicAdd(&sacc[s3 * SACC_STRIDE + colc],      fmaxf(m0[3] + tb0, 0.f));
        atomicAdd(&sacc[s3 * SACC_STRIDE + colc + 16], fmaxf(m1[3] + tb1, 0.f));
    }
    __syncthreads();

    // remove the anchor row's contribution (it was processed uniformly above)
    if (tid < 128) atomicAdd(&sacc[seg0 * SACC_STRIDE + tid], -h_anchor);
    __syncthreads();

    // flush per-block partials: scratch[b][seg][d], coalesced 4B stores
    float* dst = scratch + b * (B_SZ * D_DIM);
    for (int i = tid; i < B_SZ * D_DIM; i += 1024)
        dst[i] = sacc[(i >> 7) * SACC_STRIDE + (i & 127)];
}

// ---- reduce 256 partials, apply W2 and count*b2 ----
__global__ void k_out(const float* __restrict__ scratch, const float* __restrict__ W2,
                      const float* __restrict__ b2, const int* __restrict__ count,
                      float* __restrict__ out) {
    __shared__ float a[D_DIM];
    int s = blockIdx.x, d = threadIdx.x;     // 128 threads
    float sum = 0.f;
    const float* p = scratch + s * D_DIM + d;
#pragma unroll 4
    for (int blk = 0; blk < 256; blk++) sum += p[blk * (B_SZ * D_DIM)];
    a[d] = sum;
    __syncthreads();
    float o = (float)count[s] * b2[d];
    const float4* w = (const float4*)(W2 + d * D_DIM);
#pragma unroll
    for (int k = 0; k < 32; k++) {
        float4 wv = w[k];
        o += a[4 * k + 0] * wv.x + a[4 * k + 1] * wv.y
           + a[4 * k + 2] * wv.z + a[4 * k + 3] * wv.w;
    }
    out[s * D_DIM + d] = o;
}

extern "C" void kernel_launch(void* const* d_in, const int* in_sizes, int n_in,
                              void* d_out, int out_size, void* d_ws, size_t ws_size,
                              hipStream_t stream) {
    const float* embs = (const float*)d_in[0];
    const float* W1   = (const float*)d_in[1];
    const float* b1   = (const float*)d_in[2];
    const float* W2   = (const float*)d_in[3];
    const float* b2   = (const float*)d_in[4];
    const int*   bidx = (const int*)d_in[5];

    char* ws = (char*)d_ws;
    unsigned* w1bf_u  = (unsigned*)(ws + WS_W1BF);
    short*    w1bf    = (short*)(ws + WS_W1BF);
    int*      count   = (int*)(ws + WS_CNT);
    float*    scratch = (float*)(ws + WS_SCRATCH);

    hipMemsetAsync(count, 0, 256 * sizeof(int), stream);
    k_prep_w1<<<64, 256, 0, stream>>>(W1, w1bf_u);
    k_hist<<<512, 256, 0, stream>>>(bidx, count);
    k_main<<<256, 1024, 0, stream>>>(embs, W1, b1, w1bf, bidx, scratch);
    k_out<<<256, 128, 0, stream>>>(scratch, W2, b2, count, (float*)d_out);
}